// Round 6
// baseline (9710.906 us; speedup 1.0000x reference)
//
#include <hip/hip_runtime.h>

#define B_ 256
#define T_ 512
#define I_ 128
#define H_ 256
#define C_ 1000
#define KT 512   // unified (zero-padded) K for both layers

__device__ __forceinline__ float fsig(float x)  { return 1.0f / (1.0f + __expf(-x)); }
__device__ __forceinline__ float ftanh(float x) { return 2.0f / (1.0f + __expf(-2.0f * x)) - 1.0f; }

// Agent-scope (device-coherent, sc-bit) 16B load as two 8B atomic loads.
// Proven correct cross-XCD path (R5). Used for all cross-wg h state.
__device__ __forceinline__ float4 load_f4_coh(const float* p) {
    const unsigned long long* q = (const unsigned long long*)p;
    unsigned long long a = __hip_atomic_load(&q[0], __ATOMIC_RELAXED, __HIP_MEMORY_SCOPE_AGENT);
    unsigned long long b = __hip_atomic_load(&q[1], __ATOMIC_RELAXED, __HIP_MEMORY_SCOPE_AGENT);
    union { unsigned long long u; float f[2]; } ua, ub;
    ua.u = a; ub.u = b;
    return make_float4(ua.f[0], ua.f[1], ub.f[0], ub.f[1]);
}

// Persistent kernel, plain launch. 512 wgs x 256 thr; 64KB LDS -> 2 wg/CU.
// wgs [0,256): layer 0 at t=s; [256,512): layer 1 at t=s-1.
// Weights register-resident (64 fp32/thread); LDS only broadcasts the
// 32x512 A-panel; c-state in one register/thread; per-group 64-wg barrier.
__global__ __launch_bounds__(256, 2) void lstm_persistent(
    const float* __restrict__ x,
    const float* __restrict__ Wih0, const float* __restrict__ Whh0,
    const float* __restrict__ bih0, const float* __restrict__ bhh0,
    const float* __restrict__ Wih1, const float* __restrict__ Whh1,
    const float* __restrict__ bih1, const float* __restrict__ bhh1,
    const float* __restrict__ fcW, const float* __restrict__ fcb,
    float* __restrict__ ws, float* __restrict__ out)
{
    __shared__ float smem[16384];   // 64KB: A-panel [32][512]; aliased by red & FC

    float* h0buf = ws;                  // [2][B*H]  (sc1-atomic access only)
    float* h1buf = ws + 2 * B_ * H_;    // [2][B*H]
    unsigned* cnts = (unsigned*)(ws + 4 * B_ * H_);  // 8 counters, stride 64 u32

    const int w = blockIdx.x;
    const int layer = w >> 8;
    const int r = w & 255;
    const int bb = r >> 5;   // batch group 0..7
    const int hb = r & 31;   // h block 0..31
    unsigned* cnt = cnts + bb * 64;

    const int tid = threadIdx.x;
    // compute mapping: thread = (local row lr, K-slice sl of 64)
    const int lr = tid & 31;
    const int sl = tid >> 5;             // 0..7
    const int g = lr >> 3, j = lr & 7;
    const int gr = g * H_ + hb * 8 + j;  // global gate row
    // staging mapping: fixed f4 k-index per thread (KT/4 = 128 = pow2)
    const int k4 = (tid & 127) * 4;      // fixed element k
    const int b0 = tid >> 7;             // 0/1
    // update mapping: thread owns one (batch, hidx) cell
    const int ub = tid >> 3;             // local batch 0..31
    const int uj = tid & 7;
    const int ubg = bb * 32 + ub;
    const int uhidx = hb * 8 + uj;

    // biases for the owned hidx (4 gates)
    float biasv[4];
    {
        const float* bi = layer ? bih1 : bih0;
        const float* bh = layer ? bhh1 : bhh0;
#pragma unroll
        for (int gg = 0; gg < 4; ++gg)
            biasv[gg] = bi[gg * H_ + uhidx] + bh[gg * H_ + uhidx];
    }

    // ---- W preload into registers (once) ----
    float Wreg[64];
    {
        const float* Wih = layer ? Wih1 : Wih0;
        const float* Whh = layer ? Whh1 : Whh0;
#pragma unroll
        for (int q = 0; q < 16; ++q) {
            const int kk = sl * 64 + q * 4;
            float4 wv;
            if (layer == 0) {
                if (kk < 128)      wv = *(const float4*)(Wih + gr * I_ + kk);
                else if (kk < 384) wv = *(const float4*)(Whh + gr * H_ + (kk - 128));
                else               wv = make_float4(0.f, 0.f, 0.f, 0.f);
            } else {
                if (kk < 256)      wv = *(const float4*)(Wih + gr * H_ + kk);
                else               wv = *(const float4*)(Whh + gr * H_ + (kk - 256));
            }
            Wreg[q * 4 + 0] = wv.x; Wreg[q * 4 + 1] = wv.y;
            Wreg[q * 4 + 2] = wv.z; Wreg[q * 4 + 3] = wv.w;
        }
    }

    float creg = 0.0f;   // cell state for (ubg, uhidx) — never touches memory

    for (int s = 0; s <= T_; ++s) {
        const bool active = layer ? (s >= 1) : (s < T_);
        if (active) {
            const int t = layer ? (s - 1) : s;
            const float* hprev = (layer ? h1buf : h0buf) + ((t - 1) & 1) * B_ * H_;
            const float* hoth  = h0buf + (t & 1) * B_ * H_;   // L1: h0 current
            float* hout        = (layer ? h1buf : h0buf) + (t & 1) * B_ * H_;

            // ---- stage A panel [32][KT]: sequential b128 LDS writes ----
#pragma unroll
            for (int i = 0; i < 16; ++i) {
                const int b = b0 + 2 * i;
                const int bglob = bb * 32 + b;
                float4 v;
                if (layer == 0) {
                    if (k4 < 128)      v = *(const float4*)(x + ((size_t)bglob * T_ + t) * I_ + k4);
                    else if (k4 < 384) v = load_f4_coh(hprev + bglob * H_ + (k4 - 128));
                    else               v = make_float4(0.f, 0.f, 0.f, 0.f);
                } else {
                    if (k4 < 256)      v = load_f4_coh(hoth  + bglob * H_ + k4);
                    else               v = load_f4_coh(hprev + bglob * H_ + (k4 - 256));
                }
                *(float4*)(smem + b * KT + k4) = v;
            }
            __syncthreads();

            // ---- compute: acc[b] = A[b][sl*64..+64) . Wreg ----
            float acc[32];
#pragma unroll
            for (int bo = 0; bo < 32; bo += 4) {
                const float* a0 = smem + (bo + 0) * KT + sl * 64;
                const float* a1 = smem + (bo + 1) * KT + sl * 64;
                const float* a2 = smem + (bo + 2) * KT + sl * 64;
                const float* a3 = smem + (bo + 3) * KT + sl * 64;
                float p0 = 0.f, p1 = 0.f, p2 = 0.f, p3 = 0.f;
#pragma unroll
                for (int q = 0; q < 16; ++q) {
                    float4 v0 = *(const float4*)(a0 + q * 4);
                    float4 v1 = *(const float4*)(a1 + q * 4);
                    float4 v2 = *(const float4*)(a2 + q * 4);
                    float4 v3 = *(const float4*)(a3 + q * 4);
                    const float w0 = Wreg[q * 4 + 0], w1 = Wreg[q * 4 + 1];
                    const float w2 = Wreg[q * 4 + 2], w3 = Wreg[q * 4 + 3];
                    p0 += v0.x * w0; p0 += v0.y * w1; p0 += v0.z * w2; p0 += v0.w * w3;
                    p1 += v1.x * w0; p1 += v1.y * w1; p1 += v1.z * w2; p1 += v1.w * w3;
                    p2 += v2.x * w0; p2 += v2.y * w1; p2 += v2.z * w2; p2 += v2.w * w3;
                    p3 += v3.x * w0; p3 += v3.y * w1; p3 += v3.z * w2; p3 += v3.w * w3;
                }
                acc[bo + 0] = p0; acc[bo + 1] = p1; acc[bo + 2] = p2; acc[bo + 3] = p3;
            }
            __syncthreads();   // A-panel dead; alias red over smem

            // ---- partials: red[b*288 + j*36 + g*8 + sl]  (9216 floats) ----
#pragma unroll
            for (int b = 0; b < 32; ++b)
                smem[b * 288 + j * 36 + g * 8 + sl] = acc[b];
            __syncthreads();

            // ---- reduce 8 slices + activations + cell update ----
            {
                const float* rp = smem + ub * 288 + uj * 36;
                float gate[4];
#pragma unroll
                for (int gg = 0; gg < 4; ++gg) {
                    float4 x0 = *(const float4*)(rp + gg * 8 + 0);
                    float4 x1 = *(const float4*)(rp + gg * 8 + 4);
                    gate[gg] = ((x0.x + x0.y) + (x0.z + x0.w)) +
                               ((x1.x + x1.y) + (x1.z + x1.w)) + biasv[gg];
                }
                const float ig = fsig(gate[0]);
                const float fg = fsig(gate[1]);
                const float gv = ftanh(gate[2]);
                const float og = fsig(gate[3]);
                creg = fg * creg + ig * gv;
                const float hval = og * ftanh(creg);
                __hip_atomic_store(&hout[ubg * H_ + uhidx], hval,
                                   __ATOMIC_RELAXED, __HIP_MEMORY_SCOPE_AGENT);
            }
        }

        // ---- per-group barrier (64 wgs) — byte-identical to proven R5 ----
        __syncthreads();
        if (tid == 0) {
            __hip_atomic_fetch_add(cnt, 1u, __ATOMIC_RELAXED, __HIP_MEMORY_SCOPE_AGENT);
            const unsigned target = (unsigned)(s + 1) * 64u;
            while (__hip_atomic_load(cnt, __ATOMIC_RELAXED, __HIP_MEMORY_SCOPE_AGENT) < target) {
                __builtin_amdgcn_s_sleep(2);
            }
        }
        __syncthreads();
    }

    // ---- FC epilogue: layer-1 wg of group bb handles tile (bb, cb=hb) ----
    if (layer == 1) {
        float* As2  = smem;                // 128*36 floats
        float* Wsh2 = smem + 128 * 36;     // 128*36 floats
        const int cb = hb;
        const float* h1 = ws + 3 * B_ * H_;  // h1buf[(T-1)&1] = h1buf[1]
        const int srow = tid >> 3;
        const int kv = tid & 7;
        const int wave = tid >> 6;
        const int lane = tid & 63;
        const int br = lane >> 3;
        const int gc8 = lane & 7;
        const int crow = cb * 32 + srow;

        float acc[4][4];
#pragma unroll
        for (int a = 0; a < 4; ++a)
#pragma unroll
            for (int b = 0; b < 4; ++b) acc[a][b] = 0.0f;

        for (int cc = 0; cc < 2; ++cc) {
            const float* ap = h1 + (bb * 32 + srow) * H_ + cc * 128;
#pragma unroll
            for (int i = 0; i < 4; ++i) {
                const int kk4 = (kv + 8 * i) * 4;
                float4 va = load_f4_coh(ap + kk4);
                As2[(kk4 + 0) * 36 + srow] = va.x;
                As2[(kk4 + 1) * 36 + srow] = va.y;
                As2[(kk4 + 2) * 36 + srow] = va.z;
                As2[(kk4 + 3) * 36 + srow] = va.w;
                float4 vw = make_float4(0.f, 0.f, 0.f, 0.f);
                if (crow < C_) vw = *(const float4*)(fcW + crow * H_ + cc * 128 + kk4);
                Wsh2[(kk4 + 0) * 36 + srow] = vw.x;
                Wsh2[(kk4 + 1) * 36 + srow] = vw.y;
                Wsh2[(kk4 + 2) * 36 + srow] = vw.z;
                Wsh2[(kk4 + 3) * 36 + srow] = vw.w;
            }
            __syncthreads();
            const float* Ap = &As2[(wave * 32) * 36 + br * 4];
            const float* Wp = &Wsh2[(wave * 32) * 36 + gc8 * 4];
#pragma unroll
            for (int kk = 0; kk < 32; ++kk) {
                float4 a = *(const float4*)(Ap + kk * 36);
                float4 wv = *(const float4*)(Wp + kk * 36);
                acc[0][0] += a.x * wv.x; acc[0][1] += a.x * wv.y; acc[0][2] += a.x * wv.z; acc[0][3] += a.x * wv.w;
                acc[1][0] += a.y * wv.x; acc[1][1] += a.y * wv.y; acc[1][2] += a.y * wv.z; acc[1][3] += a.y * wv.w;
                acc[2][0] += a.z * wv.x; acc[2][1] += a.z * wv.y; acc[2][2] += a.z * wv.z; acc[2][3] += a.z * wv.w;
                acc[3][0] += a.w * wv.x; acc[3][1] += a.w * wv.y; acc[3][2] += a.w * wv.z; acc[3][3] += a.w * wv.w;
            }
            __syncthreads();
        }

        float* red = As2;
        {
            const int base = tid * 16;
#pragma unroll
            for (int a = 0; a < 4; ++a)
#pragma unroll
                for (int b = 0; b < 4; ++b)
                    red[base + a * 4 + b] = acc[a][b];
        }
        __syncthreads();
        {
            const int bl = tid >> 3;
            const int jj = tid & 7;
#pragma unroll
            for (int gg = 0; gg < 4; ++gg) {
                const int gc = gg * 8 + jj;
                const int br2 = bl >> 2, bi2 = bl & 3, gq = gc >> 2, gj = gc & 3;
                float v = 0.0f;
#pragma unroll
                for (int wv = 0; wv < 4; ++wv)
                    v += red[(wv * 64 + br2 * 8 + gq) * 16 + bi2 * 4 + gj];
                const int cglob = cb * 32 + gc;
                if (cglob < C_) {
                    v += fcb[cglob];
                    out[(size_t)(bb * 32 + bl) * C_ + cglob] = v;
                }
            }
        }
    }
}

extern "C" void kernel_launch(void* const* d_in, const int* in_sizes, int n_in,
                              void* d_out, int out_size, void* d_ws, size_t ws_size,
                              hipStream_t stream)
{
    const float* x    = (const float*)d_in[0];
    const float* Wih0 = (const float*)d_in[1];
    const float* Whh0 = (const float*)d_in[2];
    const float* bih0 = (const float*)d_in[3];
    const float* bhh0 = (const float*)d_in[4];
    const float* Wih1 = (const float*)d_in[5];
    const float* Whh1 = (const float*)d_in[6];
    const float* bih1 = (const float*)d_in[7];
    const float* bhh1 = (const float*)d_in[8];
    const float* fcW  = (const float*)d_in[9];
    const float* fcb  = (const float*)d_in[10];
    float* ws  = (float*)d_ws;
    float* out = (float*)d_out;

    // zero h0[2], h1[2] + 8 barrier counters (stride-64 u32)
    hipMemsetAsync(d_ws, 0, (size_t)(4 * B_ * H_ + 8 * 64) * sizeof(float), stream);

    lstm_persistent<<<512, 256, 0, stream>>>(
        x, Wih0, Whh0, bih0, bhh0, Wih1, Whh1, bih1, bhh1, fcW, fcb, ws, out);
}